// Round 18
// baseline (135.175 us; speedup 1.0000x reference)
//
#include <hip/hip_runtime.h>
#include <math.h>

#define R_NODES 1152
#define DIGITS 10
#define OUT_CH 16
#define IN_CH 8
#define BATCH 256
#define COLS 160            // DIGITS*OUT_CH
#define W_PER_R 1280        // DIGITS*OUT_CH*IN_CH
#define MROW 9216           // R*IN_CH
#define MSTRIDE (COLS * MROW)
#define NSPLIT 72           // K-split: 16 r-rows (K=128, 2 chunks) per block
#define RPS 16              // rows per split
#define YB_S 8              // k_s batch blocks (32 b each)
#define UP 88               // bf16 LDS row stride (64 K): 2-way alias = free
#define KST 264             // k_m LDS row stride (256 K): 132 dwords = 4 mod 32 -> 2-way free

typedef __attribute__((ext_vector_type(8))) short short8v;
typedef __attribute__((ext_vector_type(4))) float floatx4;

__device__ inline unsigned short f2bf(float x) {
    union { float f; unsigned int i; } v; v.f = x;
    unsigned int r = v.i + 0x7FFFu + ((v.i >> 16) & 1u);   // round-nearest-even
    return (unsigned short)(r >> 16);
}
__device__ inline float bf2f(unsigned short x) {
    union { unsigned int i; float f; } v; v.i = ((unsigned int)x) << 16;
    return v.f;
}

// ---------- s partials via MFMA; logits from W·M contraction ----------
// grid (72, 8). r17 analysis: k_a (2 x ~10us VALU) was the largest untouched
// item. The agreement b[r,d] = scale*sum_{b,o,i} W*u*s factors through
// M[do][ri] = sum_b s*u (a 160x9216x256 MFMA GEMM, k_m below); the remaining
// sum_{o,i} W*M is 1.5 MFLOP and folds into THIS kernel's logit phase.
__global__ __launch_bounds__(256, 3) void k_s(
    const float* __restrict__ u,      // [B][R][8]
    const float* __restrict__ W,      // [R][10][16][8]
    const float* __restrict__ Mb,     // [2][160][9216] agreement GEMM outputs
    const float* __restrict__ sqbuf,  // [3] per-iteration sum-sq
    unsigned short* __restrict__ part, // [NSPLIT][B][160] bf16
    float* __restrict__ sqz,          // slot to zero (= &sqbuf[it])
    int nbuf)
{
    __shared__ unsigned short ulds[32 * UP];    // 5.6 KB  [batch][K-chunk]
    __shared__ unsigned short wlds[COLS * UP];  // 28.2 KB [col][K-chunk]
    __shared__ float cs[RPS * DIGITS];          // 160 logits -> c

    const int split = blockIdx.x;
    const int b0 = blockIdx.y * 32;
    const int t = threadIdx.x;
    const int r0 = split * RPS;

    if (split == 0 && blockIdx.y == 0 && t == 0) *sqz = 0.f;

    // ---- 1. logits for rows r0..r0+15: sum_bu scale_bu * sum_{o,i} W*M_bu
    if (t < RPS * DIGITS) {
        float a = 0.f;
        int r_l = t / 10, d = t - r_l * 10;
        const float* Wrow = W + (size_t)(r0 + r_l) * W_PER_R + d * 128;
        for (int bu = 0; bu < nbuf; ++bu) {
            float q = sqbuf[bu];
            float sc = sqrtf(q) / (1.f + q);
            const float* Mrow = Mb + (size_t)bu * MSTRIDE
                                   + (size_t)(d * 16) * MROW + (size_t)(r0 + r_l) * 8;
            float partial = 0.f;
#pragma unroll
            for (int o = 0; o < 16; ++o) {
                const float4* wv = (const float4*)(Wrow + o * 8);
                const float4* mv = (const float4*)(Mrow + (size_t)o * MROW);
                float4 w0 = wv[0], w1 = wv[1], m0 = mv[0], m1 = mv[1];
                partial += w0.x*m0.x + w0.y*m0.y + w0.z*m0.z + w0.w*m0.w
                         + w1.x*m1.x + w1.y*m1.y + w1.z*m1.z + w1.w*m1.w;
            }
            a += sc * partial;
        }
        cs[t] = a;
    }
    __syncthreads();
    if (t < RPS) {
        float e[DIGITS];
        float m = -1e30f;
#pragma unroll
        for (int d = 0; d < DIGITS; ++d) m = fmaxf(m, cs[t*10 + d]);
        float ssum = 0.f;
#pragma unroll
        for (int d = 0; d < DIGITS; ++d) { e[d] = expf(cs[t*10 + d] - m); ssum += e[d]; }
        float inv = 1.f / ssum;
#pragma unroll
        for (int d = 0; d < DIGITS; ++d) cs[t*10 + d] = e[d] * inv;
    }
    __syncthreads();

    // ---- 2. MFMA geometry
    const int w = t >> 6, l = t & 63;
    const int mtile = w & 1;
    const int ncol0 = (w >> 1) * 5;
    const int koff = (l >> 4) * 8;
    const int arow = (mtile * 16 + (l & 15)) * UP;

    floatx4 acc[5];
#pragma unroll
    for (int j = 0; j < 5; ++j) acc[j] = (floatx4){0.f, 0.f, 0.f, 0.f};

    // ---- 3. K-chunk loop (2 chunks of K=64) -> MFMA-accumulate
    for (int ch = 0; ch < 2; ++ch) {
        const int rc = r0 + ch * 8;
        float4 uv[2];
#pragma unroll
        for (int p = 0; p < 2; ++p) {
            int idx = t + p * 256;
            int b = idx >> 4, q = idx & 15;
            uv[p] = *(const float4*)(u + (size_t)(b0 + b) * (R_NODES * IN_CH)
                                       + (size_t)rc * IN_CH + q * 4);
        }
        float4 wr[10];
        {
            const float4* Wg = (const float4*)(W + (size_t)rc * W_PER_R);
#pragma unroll
            for (int p = 0; p < 10; ++p) wr[p] = Wg[t + p * 256];
        }
        if (ch) __syncthreads();
#pragma unroll
        for (int p = 0; p < 2; ++p) {
            int idx = t + p * 256;
            int b = idx >> 4, q = idx & 15;
            *(short4*)&ulds[b * UP + q * 4] =
                make_short4((short)f2bf(uv[p].x), (short)f2bf(uv[p].y),
                            (short)f2bf(uv[p].z), (short)f2bf(uv[p].w));
        }
#pragma unroll
        for (int p = 0; p < 10; ++p) {
            int e4 = t + p * 256;
            int e  = e4 * 4;
            int r_l = e4 / 320;
            int rem = e - r_l * W_PER_R;
            int col = rem >> 3;
            int i0  = e & 7;
            float cv = cs[(ch * 8 + r_l) * 10 + (rem >> 7)];
            float4 w4 = wr[p];
            *(short4*)&wlds[col * UP + r_l * 8 + i0] =
                make_short4((short)f2bf(w4.x * cv), (short)f2bf(w4.y * cv),
                            (short)f2bf(w4.z * cv), (short)f2bf(w4.w * cv));
        }
        __syncthreads();
        short8v a0 = *(const short8v*)&ulds[arow + koff];
        short8v a1 = *(const short8v*)&ulds[arow + 32 + koff];
#pragma unroll
        for (int j = 0; j < 5; ++j) {
            const int bcol = ((ncol0 + j) * 16 + (l & 15)) * UP;
            short8v bb0 = *(const short8v*)&wlds[bcol + koff];
            short8v bb1 = *(const short8v*)&wlds[bcol + 32 + koff];
            acc[j] = __builtin_amdgcn_mfma_f32_16x16x32_bf16(a0, bb0, acc[j], 0, 0, 0);
            acc[j] = __builtin_amdgcn_mfma_f32_16x16x32_bf16(a1, bb1, acc[j], 0, 0, 0);
        }
    }

    // ---- 4. store bf16 partials
    unsigned short* pp = part + (size_t)split * (BATCH * COLS);
    const int gb = b0 + mtile * 16 + (l >> 4) * 4;
#pragma unroll
    for (int j = 0; j < 5; ++j) {
        const int gc = (ncol0 + j) * 16 + (l & 15);
#pragma unroll
        for (int reg = 0; reg < 4; ++reg)
            pp[(size_t)(gb + reg) * COLS + gc] = f2bf(acc[j][reg]);
    }
}

// ---------- reduce bf16 partials -> s ; accumulate sum-sq into sqbuf[it] ----------
__global__ void k_sq(const unsigned short* __restrict__ part,
                     float* __restrict__ s,
                     float* __restrict__ sq)
{
    const int t = threadIdx.x;
    const int e0 = blockIdx.x * 64;
    const int el = t & 63, q = t >> 6;
    float v = 0.f;
    for (int sp = q; sp < NSPLIT; sp += 4)
        v += bf2f(part[(size_t)sp * (BATCH * COLS) + e0 + el]);
    __shared__ float red[256];
    red[t] = v;
    __syncthreads();
    if (t < 64) {
        float vv = red[t] + red[t + 64] + red[t + 128] + red[t + 192];
        s[e0 + t] = vv;
        float x = vv * vv;
#pragma unroll
        for (int off = 32; off > 0; off >>= 1)
            x += __shfl_down(x, off, 64);
        if (t == 0) atomicAdd(sq, x);
    }
}

// ---------- agreement GEMM: M[do][ri] = sum_b s[b,do]*u[b,ri]  (MFMA, K=256) ----------
// grid (144, 10): blockIdx.x = 64-ri group, blockIdx.y = 16-do tile.
// Both operands staged TRANSPOSED (K=b contiguous) in bf16 LDS, stride 264.
// 4 waves: wave w -> ri-tile w. 8 K-steps x 1 MFMA each.
__global__ __launch_bounds__(256, 3) void k_m(
    const float* __restrict__ u,     // [B][9216]
    const float* __restrict__ s,     // [B][160]
    float* __restrict__ M)           // [160][9216]
{
    __shared__ unsigned short sld[16 * KST];   // 8.4 KB
    __shared__ unsigned short uld[64 * KST];   // 33.8 KB
    const int t = threadIdx.x;
    const int rig = blockIdx.x;
    const int do0 = blockIdx.y * 16;

    // stage s-slice transposed: sld[c][b] = s[b][do0+c]
#pragma unroll
    for (int p = 0; p < 4; ++p) {
        int idx = t + p * 256;       // 0..1023
        int b = idx >> 2, q = idx & 3;
        float4 v = *(const float4*)(s + (size_t)b * COLS + do0 + q * 4);
        sld[(q*4+0)*KST + b] = f2bf(v.x);
        sld[(q*4+1)*KST + b] = f2bf(v.y);
        sld[(q*4+2)*KST + b] = f2bf(v.z);
        sld[(q*4+3)*KST + b] = f2bf(v.w);
    }
    // stage u-slice transposed: uld[c][b] = u[b][rig*64+c]
#pragma unroll
    for (int p = 0; p < 16; ++p) {
        int idx = t + p * 256;       // 0..4095
        int b = idx >> 4, q = idx & 15;
        float4 v = *(const float4*)(u + (size_t)b * MROW + rig * 64 + q * 4);
        uld[(q*4+0)*KST + b] = f2bf(v.x);
        uld[(q*4+1)*KST + b] = f2bf(v.y);
        uld[(q*4+2)*KST + b] = f2bf(v.z);
        uld[(q*4+3)*KST + b] = f2bf(v.w);
    }
    __syncthreads();

    const int w = t >> 6, l = t & 63;
    floatx4 acc = {0.f, 0.f, 0.f, 0.f};
#pragma unroll
    for (int ks = 0; ks < 8; ++ks) {
        int koff = ks * 32 + (l >> 4) * 8;
        short8v av = *(const short8v*)&sld[(l & 15) * KST + koff];
        short8v bv = *(const short8v*)&uld[(w * 16 + (l & 15)) * KST + koff];
        acc = __builtin_amdgcn_mfma_f32_16x16x32_bf16(av, bv, acc, 0, 0, 0);
    }
    const int ri = rig * 64 + w * 16 + (l & 15);
    const int dor = do0 + (l >> 4) * 4;
#pragma unroll
    for (int reg = 0; reg < 4; ++reg)
        M[(size_t)(dor + reg) * MROW + ri] = acc[reg];
}

// ---------- final output: v = s * sqrt(sq)/(1+sq) ----------
__global__ void k_scale(const float* __restrict__ s,
                        const float* __restrict__ sq,
                        float* __restrict__ out)
{
    int e = blockIdx.x * 256 + threadIdx.x;
    float q = *sq;
    float scale = sqrtf(q) / (1.f + q);
    out[e] = s[e] * scale;
}

extern "C" void kernel_launch(void* const* d_in, const int* in_sizes, int n_in,
                              void* d_out, int out_size, void* d_ws, size_t ws_size,
                              hipStream_t stream)
{
    const float* u = (const float*)d_in[0];   // (256, 1152, 8)
    const float* W = (const float*)d_in[1];   // (1, 1152, 10, 16, 8)
    float* out = (float*)d_out;               // (256, 10, 16)
    float* ws = (float*)d_ws;

    float* s     = ws;                         // 40960 floats
    float* sqbuf = ws + 40960;                 // 3 (+pad to 64)
    float* M     = ws + 41024;                 // 2 * 1474560
    unsigned short* part = (unsigned short*)(ws + 41024 + 2 * MSTRIDE);  // 72*40960 bf16

    for (int it = 0; it < 3; ++it) {
        k_s<<<dim3(NSPLIT, YB_S), dim3(256), 0, stream>>>(u, W, M, sqbuf, part,
                                                          sqbuf + it, it);
        k_sq<<<dim3(BATCH * COLS / 64), dim3(256), 0, stream>>>(part, s, sqbuf + it);
        if (it < 2)
            k_m<<<dim3(144, 10), dim3(256), 0, stream>>>(u, s, M + (size_t)it * MSTRIDE);
        else
            k_scale<<<dim3(BATCH * COLS / 256), dim3(256), 0, stream>>>(s, sqbuf + 2, out);
    }
}

// Round 19
// 104.099 us; speedup vs baseline: 1.2985x; 1.2985x over previous
//
#include <hip/hip_runtime.h>
#include <math.h>

#define R_NODES 1152
#define DIGITS 10
#define OUT_CH 16
#define IN_CH 8
#define BATCH 256
#define COLS 160            // DIGITS*OUT_CH
#define W_PER_R 1280        // DIGITS*OUT_CH*IN_CH
#define MROW 9216           // R*IN_CH
#define NSPLIT 72           // K-split: 16 r-rows (K=128, 2 chunks) per block
#define RPS 16              // rows per split
#define YB_S 8              // k_s batch blocks (32 b each)
#define UP 88               // bf16 LDS row stride (64 K): 2-way alias = free
#define KST 264             // k_b LDS row stride (256 K bf16)

typedef __attribute__((ext_vector_type(8))) short short8v;
typedef __attribute__((ext_vector_type(4))) float floatx4;

__device__ inline unsigned short f2bf(float x) {
    union { float f; unsigned int i; } v; v.f = x;
    unsigned int r = v.i + 0x7FFFu + ((v.i >> 16) & 1u);   // round-nearest-even
    return (unsigned short)(r >> 16);
}
__device__ inline float bf2f(unsigned short x) {
    union { unsigned int i; float f; } v; v.i = ((unsigned int)x) << 16;
    return v.f;
}

// ---------- s partials via MFMA; logits read directly from blog ----------
// grid (72, 8). r18 lesson: the W*M contraction must happen in-register in
// the GEMM kernel (k_b) — materializing M cost 33us of traffic+gather. k_s
// reverts to the r17 structure; its logit phase is one coalesced blog read.
__global__ __launch_bounds__(256, 3) void k_s(
    const float* __restrict__ u,      // [B][R][8]
    const float* __restrict__ W,      // [R][10][16][8]
    const float* __restrict__ blog,   // [R][10] routing logits (scale-applied)
    unsigned short* __restrict__ part, // [NSPLIT][B][160] bf16
    float* __restrict__ sqz,          // slot to zero (= &sqbuf[it])
    int nbuf)
{
    __shared__ unsigned short ulds[32 * UP];    // 5.6 KB  [batch][K-chunk]
    __shared__ unsigned short wlds[COLS * UP];  // 28.2 KB [col][K-chunk]
    __shared__ float cs[RPS * DIGITS];          // 160 logits -> c

    const int split = blockIdx.x;
    const int b0 = blockIdx.y * 32;
    const int t = threadIdx.x;
    const int r0 = split * RPS;

    if (split == 0 && blockIdx.y == 0 && t == 0) *sqz = 0.f;

    // ---- 1. logits for rows r0..r0+15 (coalesced; 0 if nbuf==0 -> c = 0.1)
    if (t < RPS * DIGITS) {
        cs[t] = nbuf ? blog[r0 * DIGITS + t] : 0.f;
    }
    __syncthreads();
    if (t < RPS) {
        float e[DIGITS];
        float m = -1e30f;
#pragma unroll
        for (int d = 0; d < DIGITS; ++d) m = fmaxf(m, cs[t*10 + d]);
        float ssum = 0.f;
#pragma unroll
        for (int d = 0; d < DIGITS; ++d) { e[d] = expf(cs[t*10 + d] - m); ssum += e[d]; }
        float inv = 1.f / ssum;
#pragma unroll
        for (int d = 0; d < DIGITS; ++d) cs[t*10 + d] = e[d] * inv;
    }
    __syncthreads();

    // ---- 2. MFMA geometry
    const int w = t >> 6, l = t & 63;
    const int mtile = w & 1;
    const int ncol0 = (w >> 1) * 5;
    const int koff = (l >> 4) * 8;
    const int arow = (mtile * 16 + (l & 15)) * UP;

    floatx4 acc[5];
#pragma unroll
    for (int j = 0; j < 5; ++j) acc[j] = (floatx4){0.f, 0.f, 0.f, 0.f};

    // ---- 3. K-chunk loop (2 chunks of K=64) -> MFMA-accumulate
    for (int ch = 0; ch < 2; ++ch) {
        const int rc = r0 + ch * 8;
        float4 uv[2];
#pragma unroll
        for (int p = 0; p < 2; ++p) {
            int idx = t + p * 256;
            int b = idx >> 4, q = idx & 15;
            uv[p] = *(const float4*)(u + (size_t)(b0 + b) * (R_NODES * IN_CH)
                                       + (size_t)rc * IN_CH + q * 4);
        }
        float4 wr[10];
        {
            const float4* Wg = (const float4*)(W + (size_t)rc * W_PER_R);
#pragma unroll
            for (int p = 0; p < 10; ++p) wr[p] = Wg[t + p * 256];
        }
        if (ch) __syncthreads();
#pragma unroll
        for (int p = 0; p < 2; ++p) {
            int idx = t + p * 256;
            int b = idx >> 4, q = idx & 15;
            *(short4*)&ulds[b * UP + q * 4] =
                make_short4((short)f2bf(uv[p].x), (short)f2bf(uv[p].y),
                            (short)f2bf(uv[p].z), (short)f2bf(uv[p].w));
        }
#pragma unroll
        for (int p = 0; p < 10; ++p) {
            int e4 = t + p * 256;
            int e  = e4 * 4;
            int r_l = e4 / 320;
            int rem = e - r_l * W_PER_R;
            int col = rem >> 3;
            int i0  = e & 7;
            float cv = cs[(ch * 8 + r_l) * 10 + (rem >> 7)];
            float4 w4 = wr[p];
            *(short4*)&wlds[col * UP + r_l * 8 + i0] =
                make_short4((short)f2bf(w4.x * cv), (short)f2bf(w4.y * cv),
                            (short)f2bf(w4.z * cv), (short)f2bf(w4.w * cv));
        }
        __syncthreads();
        short8v a0 = *(const short8v*)&ulds[arow + koff];
        short8v a1 = *(const short8v*)&ulds[arow + 32 + koff];
#pragma unroll
        for (int j = 0; j < 5; ++j) {
            const int bcol = ((ncol0 + j) * 16 + (l & 15)) * UP;
            short8v bb0 = *(const short8v*)&wlds[bcol + koff];
            short8v bb1 = *(const short8v*)&wlds[bcol + 32 + koff];
            acc[j] = __builtin_amdgcn_mfma_f32_16x16x32_bf16(a0, bb0, acc[j], 0, 0, 0);
            acc[j] = __builtin_amdgcn_mfma_f32_16x16x32_bf16(a1, bb1, acc[j], 0, 0, 0);
        }
    }

    // ---- 4. store bf16 partials
    unsigned short* pp = part + (size_t)split * (BATCH * COLS);
    const int gb = b0 + mtile * 16 + (l >> 4) * 4;
#pragma unroll
    for (int j = 0; j < 5; ++j) {
        const int gc = (ncol0 + j) * 16 + (l & 15);
#pragma unroll
        for (int reg = 0; reg < 4; ++reg)
            pp[(size_t)(gb + reg) * COLS + gc] = f2bf(acc[j][reg]);
    }
}

// ---------- reduce bf16 partials -> s ; accumulate sum-sq into sqbuf[it] ----------
__global__ void k_sq(const unsigned short* __restrict__ part,
                     float* __restrict__ s,
                     float* __restrict__ sq)
{
    const int t = threadIdx.x;
    const int e0 = blockIdx.x * 64;
    const int el = t & 63, q = t >> 6;
    float v = 0.f;
    for (int sp = q; sp < NSPLIT; sp += 4)
        v += bf2f(part[(size_t)sp * (BATCH * COLS) + e0 + el]);
    __shared__ float red[256];
    red[t] = v;
    __syncthreads();
    if (t < 64) {
        float vv = red[t] + red[t + 64] + red[t + 128] + red[t + 192];
        s[e0 + t] = vv;
        float x = vv * vv;
#pragma unroll
        for (int off = 32; off > 0; off >>= 1)
            x += __shfl_down(x, off, 64);
        if (t == 0) atomicAdd(sq, x);
    }
}

// ---------- agreement: blog[r,d] (+)= scale * sum_{o,i} W * M[do][ri] ----------
// M[do][ri] = sum_b s[b,do]*u[b,ri] computed in MFMA accs, contracted with W
// IN-REGISTER (never materialized). grid (144, 10): blockIdx.x = 64-ri group
// (8 r-rows), blockIdx.y = digit d. Lane (w,l) reg holds
// M[o=(l>>4)*4+reg][ri=w*16+(l&15)]; r_l = 2w+((l&15)>>3), i = l&7.
// shfl_xor over o-bits (16,32) and i-bits (1,2,4) -> complete logit for
// (r0+2w+bit3, d). Single deterministic writer per (r,d).
__global__ __launch_bounds__(256, 3) void k_b(
    const float* __restrict__ u,     // [B][9216]
    const float* __restrict__ s,     // [B][160]
    const float* __restrict__ W,     // [R][10][16][8]
    const float* __restrict__ sqp,   // &sqbuf[it]
    float* __restrict__ blog,        // [R][10]
    int first)
{
    __shared__ unsigned short sld[16 * KST];   // 8.4 KB  [o][b]
    __shared__ unsigned short uld[64 * KST];   // 33.8 KB [ri][b]
    const int t = threadIdx.x;
    const int rig = blockIdx.x;
    const int d = blockIdx.y;

    // stage s-slice transposed: sld[o][b] = s[b][d*16+o]
#pragma unroll
    for (int p = 0; p < 4; ++p) {
        int idx = t + p * 256;       // 0..1023
        int b = idx >> 2, q = idx & 3;
        float4 v = *(const float4*)(s + (size_t)b * COLS + d * 16 + q * 4);
        sld[(q*4+0)*KST + b] = f2bf(v.x);
        sld[(q*4+1)*KST + b] = f2bf(v.y);
        sld[(q*4+2)*KST + b] = f2bf(v.z);
        sld[(q*4+3)*KST + b] = f2bf(v.w);
    }
    // stage u-slice transposed: uld[c][b] = u[b][rig*64+c]
#pragma unroll
    for (int p = 0; p < 16; ++p) {
        int idx = t + p * 256;       // 0..4095
        int b = idx >> 4, q = idx & 15;
        float4 v = *(const float4*)(u + (size_t)b * MROW + rig * 64 + q * 4);
        uld[(q*4+0)*KST + b] = f2bf(v.x);
        uld[(q*4+1)*KST + b] = f2bf(v.y);
        uld[(q*4+2)*KST + b] = f2bf(v.z);
        uld[(q*4+3)*KST + b] = f2bf(v.w);
    }
    __syncthreads();

    const int w = t >> 6, l = t & 63;
    floatx4 acc = {0.f, 0.f, 0.f, 0.f};
#pragma unroll
    for (int ks = 0; ks < 8; ++ks) {
        int koff = ks * 32 + (l >> 4) * 8;
        short8v av = *(const short8v*)&sld[(l & 15) * KST + koff];
        short8v bv = *(const short8v*)&uld[(w * 16 + (l & 15)) * KST + koff];
        acc = __builtin_amdgcn_mfma_f32_16x16x32_bf16(av, bv, acc, 0, 0, 0);
    }

    // in-register contraction with W
    const int r_l = 2 * w + ((l & 15) >> 3);
    const int r = rig * 8 + r_l;
    const float* Wp = W + (size_t)r * W_PER_R + d * 128 + (l & 7);
    float p = 0.f;
#pragma unroll
    for (int reg = 0; reg < 4; ++reg) {
        int o = (l >> 4) * 4 + reg;
        p = fmaf(Wp[o * 8], acc[reg], p);
    }
    p += __shfl_xor(p, 1, 64);
    p += __shfl_xor(p, 2, 64);
    p += __shfl_xor(p, 4, 64);
    p += __shfl_xor(p, 16, 64);
    p += __shfl_xor(p, 32, 64);

    if ((l & 55) == 0) {   // l == 0 or 8: one writer per (r, d)
        float q = *sqp;
        float scale = sqrtf(q) / (1.f + q);
        float prev = first ? 0.f : blog[r * DIGITS + d];
        blog[r * DIGITS + d] = prev + scale * p;
    }
}

// ---------- final output: v = s * sqrt(sq)/(1+sq) ----------
__global__ void k_scale(const float* __restrict__ s,
                        const float* __restrict__ sq,
                        float* __restrict__ out)
{
    int e = blockIdx.x * 256 + threadIdx.x;
    float q = *sq;
    float scale = sqrtf(q) / (1.f + q);
    out[e] = s[e] * scale;
}

extern "C" void kernel_launch(void* const* d_in, const int* in_sizes, int n_in,
                              void* d_out, int out_size, void* d_ws, size_t ws_size,
                              hipStream_t stream)
{
    const float* u = (const float*)d_in[0];   // (256, 1152, 8)
    const float* W = (const float*)d_in[1];   // (1, 1152, 10, 16, 8)
    float* out = (float*)d_out;               // (256, 10, 16)
    float* ws = (float*)d_ws;

    float* s     = ws;                         // 40960 floats
    float* sqbuf = ws + 40960;                 // 3 (+pad to 64)
    float* blog  = ws + 41024;                 // 11520
    unsigned short* part = (unsigned short*)(ws + 41024 + 11520 + 64);  // 72*40960 bf16

    for (int it = 0; it < 3; ++it) {
        k_s<<<dim3(NSPLIT, YB_S), dim3(256), 0, stream>>>(u, W, blog, part,
                                                          sqbuf + it, it);
        k_sq<<<dim3(BATCH * COLS / 64), dim3(256), 0, stream>>>(part, s, sqbuf + it);
        if (it < 2)
            k_b<<<dim3(144, 10), dim3(256), 0, stream>>>(u, s, W, sqbuf + it,
                                                         blog, it == 0 ? 1 : 0);
        else
            k_scale<<<dim3(BATCH * COLS / 256), dim3(256), 0, stream>>>(s, sqbuf + 2, out);
    }
}

// Round 20
// 95.934 us; speedup vs baseline: 1.4090x; 1.0851x over previous
//
#include <hip/hip_runtime.h>
#include <math.h>

#define R_NODES 1152
#define DIGITS 10
#define OUT_CH 16
#define IN_CH 8
#define BATCH 256
#define COLS 160            // DIGITS*OUT_CH
#define W_PER_R 1280        // DIGITS*OUT_CH*IN_CH
#define MROW 9216           // R*IN_CH
#define NSPLIT 72           // K-split: 16 r-rows (K=128, 2 chunks) per block
#define RPS 16              // rows per split
#define YB_S 8              // k_s batch blocks (32 b each)
#define UP 88               // bf16 LDS row stride (64 K): 2-way alias = free
#define KB 72               // k_b LDS row stride (64 K bf16): 16B-aligned rows
#define BLOG_N 11520        // R*DIGITS

typedef __attribute__((ext_vector_type(8))) short short8v;
typedef __attribute__((ext_vector_type(4))) float floatx4;

__device__ inline unsigned short f2bf(float x) {
    union { float f; unsigned int i; } v; v.f = x;
    unsigned int r = v.i + 0x7FFFu + ((v.i >> 16) & 1u);   // round-nearest-even
    return (unsigned short)(r >> 16);
}
__device__ inline float bf2f(unsigned short x) {
    union { unsigned int i; float f; } v; v.i = ((unsigned int)x) << 16;
    return v.f;
}

// ---------- s partials via MFMA; logits = sum of 4 blog partial slots ----------
__global__ __launch_bounds__(256, 3) void k_s(
    const float* __restrict__ u,      // [B][R][8]
    const float* __restrict__ W,      // [R][10][16][8]
    const float* __restrict__ blog4,  // [4][R][10] partial logits (scale-applied)
    unsigned short* __restrict__ part, // [NSPLIT][B][160] bf16
    float* __restrict__ sqz,          // slot to zero (= &sqbuf[it])
    int nbuf)
{
    __shared__ unsigned short ulds[32 * UP];    // 5.6 KB  [batch][K-chunk]
    __shared__ unsigned short wlds[COLS * UP];  // 28.2 KB [col][K-chunk]
    __shared__ float cs[RPS * DIGITS];          // 160 logits -> c

    const int split = blockIdx.x;
    const int b0 = blockIdx.y * 32;
    const int t = threadIdx.x;
    const int r0 = split * RPS;

    if (split == 0 && blockIdx.y == 0 && t == 0) *sqz = 0.f;

    // ---- 1. logits for rows r0..r0+15 (4 coalesced slot reads)
    if (t < RPS * DIGITS) {
        float a = 0.f;
        if (nbuf) {
            a = blog4[r0 * DIGITS + t]
              + blog4[BLOG_N + r0 * DIGITS + t]
              + blog4[2 * BLOG_N + r0 * DIGITS + t]
              + blog4[3 * BLOG_N + r0 * DIGITS + t];
        }
        cs[t] = a;
    }
    __syncthreads();
    if (t < RPS) {
        float e[DIGITS];
        float m = -1e30f;
#pragma unroll
        for (int d = 0; d < DIGITS; ++d) m = fmaxf(m, cs[t*10 + d]);
        float ssum = 0.f;
#pragma unroll
        for (int d = 0; d < DIGITS; ++d) { e[d] = expf(cs[t*10 + d] - m); ssum += e[d]; }
        float inv = 1.f / ssum;
#pragma unroll
        for (int d = 0; d < DIGITS; ++d) cs[t*10 + d] = e[d] * inv;
    }
    __syncthreads();

    // ---- 2. MFMA geometry
    const int w = t >> 6, l = t & 63;
    const int mtile = w & 1;
    const int ncol0 = (w >> 1) * 5;
    const int koff = (l >> 4) * 8;
    const int arow = (mtile * 16 + (l & 15)) * UP;

    floatx4 acc[5];
#pragma unroll
    for (int j = 0; j < 5; ++j) acc[j] = (floatx4){0.f, 0.f, 0.f, 0.f};

    // ---- 3. K-chunk loop (2 chunks of K=64) -> MFMA-accumulate
    for (int ch = 0; ch < 2; ++ch) {
        const int rc = r0 + ch * 8;
        float4 uv[2];
#pragma unroll
        for (int p = 0; p < 2; ++p) {
            int idx = t + p * 256;
            int b = idx >> 4, q = idx & 15;
            uv[p] = *(const float4*)(u + (size_t)(b0 + b) * (R_NODES * IN_CH)
                                       + (size_t)rc * IN_CH + q * 4);
        }
        float4 wr[10];
        {
            const float4* Wg = (const float4*)(W + (size_t)rc * W_PER_R);
#pragma unroll
            for (int p = 0; p < 10; ++p) wr[p] = Wg[t + p * 256];
        }
        if (ch) __syncthreads();
#pragma unroll
        for (int p = 0; p < 2; ++p) {
            int idx = t + p * 256;
            int b = idx >> 4, q = idx & 15;
            *(short4*)&ulds[b * UP + q * 4] =
                make_short4((short)f2bf(uv[p].x), (short)f2bf(uv[p].y),
                            (short)f2bf(uv[p].z), (short)f2bf(uv[p].w));
        }
#pragma unroll
        for (int p = 0; p < 10; ++p) {
            int e4 = t + p * 256;
            int e  = e4 * 4;
            int r_l = e4 / 320;
            int rem = e - r_l * W_PER_R;
            int col = rem >> 3;
            int i0  = e & 7;
            float cv = cs[(ch * 8 + r_l) * 10 + (rem >> 7)];
            float4 w4 = wr[p];
            *(short4*)&wlds[col * UP + r_l * 8 + i0] =
                make_short4((short)f2bf(w4.x * cv), (short)f2bf(w4.y * cv),
                            (short)f2bf(w4.z * cv), (short)f2bf(w4.w * cv));
        }
        __syncthreads();
        short8v a0 = *(const short8v*)&ulds[arow + koff];
        short8v a1 = *(const short8v*)&ulds[arow + 32 + koff];
#pragma unroll
        for (int j = 0; j < 5; ++j) {
            const int bcol = ((ncol0 + j) * 16 + (l & 15)) * UP;
            short8v bb0 = *(const short8v*)&wlds[bcol + koff];
            short8v bb1 = *(const short8v*)&wlds[bcol + 32 + koff];
            acc[j] = __builtin_amdgcn_mfma_f32_16x16x32_bf16(a0, bb0, acc[j], 0, 0, 0);
            acc[j] = __builtin_amdgcn_mfma_f32_16x16x32_bf16(a1, bb1, acc[j], 0, 0, 0);
        }
    }

    // ---- 4. store bf16 partials
    unsigned short* pp = part + (size_t)split * (BATCH * COLS);
    const int gb = b0 + mtile * 16 + (l >> 4) * 4;
#pragma unroll
    for (int j = 0; j < 5; ++j) {
        const int gc = (ncol0 + j) * 16 + (l & 15);
#pragma unroll
        for (int reg = 0; reg < 4; ++reg)
            pp[(size_t)(gb + reg) * COLS + gc] = f2bf(acc[j][reg]);
    }
}

// ---------- reduce bf16 partials -> s ; accumulate sum-sq into sqbuf[it] ----------
__global__ void k_sq(const unsigned short* __restrict__ part,
                     float* __restrict__ s,
                     float* __restrict__ sq)
{
    const int t = threadIdx.x;
    const int e0 = blockIdx.x * 64;
    const int el = t & 63, q = t >> 6;
    float v = 0.f;
    for (int sp = q; sp < NSPLIT; sp += 4)
        v += bf2f(part[(size_t)sp * (BATCH * COLS) + e0 + el]);
    __shared__ float red[256];
    red[t] = v;
    __syncthreads();
    if (t < 64) {
        float vv = red[t] + red[t + 64] + red[t + 128] + red[t + 192];
        s[e0 + t] = vv;
        float x = vv * vv;
#pragma unroll
        for (int off = 32; off > 0; off >>= 1)
            x += __shfl_down(x, off, 64);
        if (t == 0) atomicAdd(sq, x);
    }
}

// ---------- agreement: blog4[bq][r,d] (+)= scale * sum_{o,i} W * M_bq[do][ri] ----------
// M_bq[do][ri] = sum_{b in quarter} s[b,do]*u[b,ri], in MFMA accs, contracted
// with W in-register. grid (144, 4): blockIdx.x = 64-ri group (8 r-rows),
// blockIdx.y = 64-batch quarter. u-slice staged ONCE (r19 waste: 10x per-d
// restage, 94MB); then 10 light per-d phases: stage s-slice (1 f4 + 4 LDS st
// per thread), 2 MFMA (K=64), contract, shfl-reduce, single-writer store.
__global__ __launch_bounds__(256, 3) void k_b(
    const float* __restrict__ u,     // [B][9216]
    const float* __restrict__ s,     // [B][160]
    const float* __restrict__ W,     // [R][10][16][8]
    const float* __restrict__ sqp,   // &sqbuf[it]
    float* __restrict__ blog4,       // [4][R][10]
    int first)
{
    __shared__ unsigned short uld[64 * KB];   // 9.2 KB [ri][b]
    __shared__ unsigned short sld[16 * KB];   // 2.3 KB [o][b]
    const int t = threadIdx.x;
    const int rig = blockIdx.x;
    const int bq = blockIdx.y;
    const int b0 = bq * 64;

    // stage u-slice transposed (once): uld[c][b] = u[b0+b][rig*64+c]
#pragma unroll
    for (int p = 0; p < 4; ++p) {
        int idx = t + p * 256;       // 0..1023
        int b = idx >> 4, q = idx & 15;
        float4 v = *(const float4*)(u + (size_t)(b0 + b) * MROW + rig * 64 + q * 4);
        uld[(q*4+0)*KB + b] = f2bf(v.x);
        uld[(q*4+1)*KB + b] = f2bf(v.y);
        uld[(q*4+2)*KB + b] = f2bf(v.z);
        uld[(q*4+3)*KB + b] = f2bf(v.w);
    }

    const int w = t >> 6, l = t & 63;
    const float q0 = *sqp;
    const float scale = sqrtf(q0) / (1.f + q0);
    const int r_l = 2 * w + ((l & 15) >> 3);
    const int r = rig * 8 + r_l;
    float* slot = blog4 + (size_t)bq * BLOG_N;

    for (int d = 0; d < DIGITS; ++d) {
        // stage s-slice transposed: sld[o][b] = s[b0+b][d*16+o]
        int sb = t >> 2, sq_ = t & 3;
        float4 v = *(const float4*)(s + (size_t)(b0 + sb) * COLS + d * 16 + sq_ * 4);
        if (d) __syncthreads();    // prev d's MFMA readers done
        sld[(sq_*4+0)*KB + sb] = f2bf(v.x);
        sld[(sq_*4+1)*KB + sb] = f2bf(v.y);
        sld[(sq_*4+2)*KB + sb] = f2bf(v.z);
        sld[(sq_*4+3)*KB + sb] = f2bf(v.w);
        __syncthreads();

        floatx4 acc = {0.f, 0.f, 0.f, 0.f};
#pragma unroll
        for (int ks = 0; ks < 2; ++ks) {
            int koff = ks * 32 + (l >> 4) * 8;
            short8v av = *(const short8v*)&sld[(l & 15) * KB + koff];
            short8v bv = *(const short8v*)&uld[(w * 16 + (l & 15)) * KB + koff];
            acc = __builtin_amdgcn_mfma_f32_16x16x32_bf16(av, bv, acc, 0, 0, 0);
        }

        // in-register contraction with W
        const float* Wp = W + (size_t)r * W_PER_R + d * 128 + (l & 7);
        float p = 0.f;
#pragma unroll
        for (int reg = 0; reg < 4; ++reg) {
            int o = (l >> 4) * 4 + reg;
            p = fmaf(Wp[o * 8], acc[reg], p);
        }
        p += __shfl_xor(p, 1, 64);
        p += __shfl_xor(p, 2, 64);
        p += __shfl_xor(p, 4, 64);
        p += __shfl_xor(p, 16, 64);
        p += __shfl_xor(p, 32, 64);

        if ((l & 55) == 0) {   // l == 0 or 8: one writer per (r, d)
            float prev = first ? 0.f : slot[r * DIGITS + d];
            slot[r * DIGITS + d] = prev + scale * p;
        }
    }
}

// ---------- final output: v = s * sqrt(sq)/(1+sq) ----------
__global__ void k_scale(const float* __restrict__ s,
                        const float* __restrict__ sq,
                        float* __restrict__ out)
{
    int e = blockIdx.x * 256 + threadIdx.x;
    float q = *sq;
    float scale = sqrtf(q) / (1.f + q);
    out[e] = s[e] * scale;
}

extern "C" void kernel_launch(void* const* d_in, const int* in_sizes, int n_in,
                              void* d_out, int out_size, void* d_ws, size_t ws_size,
                              hipStream_t stream)
{
    const float* u = (const float*)d_in[0];   // (256, 1152, 8)
    const float* W = (const float*)d_in[1];   // (1, 1152, 10, 16, 8)
    float* out = (float*)d_out;               // (256, 10, 16)
    float* ws = (float*)d_ws;

    float* s     = ws;                         // 40960 floats
    float* sqbuf = ws + 40960;                 // 3 (+pad to 64)
    float* blog4 = ws + 41024;                 // 4 * 11520
    unsigned short* part = (unsigned short*)(ws + 41024 + 4 * BLOG_N + 64);  // 72*40960 bf16

    for (int it = 0; it < 3; ++it) {
        k_s<<<dim3(NSPLIT, YB_S), dim3(256), 0, stream>>>(u, W, blog4, part,
                                                          sqbuf + it, it);
        k_sq<<<dim3(BATCH * COLS / 64), dim3(256), 0, stream>>>(part, s, sqbuf + it);
        if (it < 2)
            k_b<<<dim3(144, 4), dim3(256), 0, stream>>>(u, s, W, sqbuf + it,
                                                        blog4, it == 0 ? 1 : 0);
        else
            k_scale<<<dim3(BATCH * COLS / 256), dim3(256), 0, stream>>>(s, sqbuf + 2, out);
    }
}